// Round 9
// baseline (20627.185 us; speedup 1.0000x reference)
//
#include <hip/hip_runtime.h>

constexpr int SEQ  = 4096;   // timesteps
constexpr int IN   = 512;    // input size
constexpr int RS   = 2048;   // reservoir size
constexpr int GB   = 256;    // blocks in scan kernel (2 waves each)
constexpr int BT   = 128;    // threads per block in scan kernel
constexpr int RING = 8;      // ring depth (epochs); skew bound <= 1
constexpr float INV_SQRT = 0.022097086912079612f; // 1/sqrt(2048)

// ---------------------------------------------------------------------------
// Phase 1: pre = X @ W_in^T, written to out rows 1..SEQ (in-place scan buffer)
// ---------------------------------------------------------------------------
__global__ __launch_bounds__(256)
void gemm_pre_kernel(const float* __restrict__ A, const float* __restrict__ B,
                     float* __restrict__ out) {
    __shared__ float As[64][17];
    __shared__ float Bs[64][17];
    const int tid = threadIdx.x;
    const int tx = tid & 15, ty = tid >> 4;
    const int m0 = blockIdx.x * 64, n0 = blockIdx.y * 64;
    const int lr = tid >> 2;
    const int lk = (tid & 3) * 4;
    float acc[4][4] = {};
    for (int k0 = 0; k0 < IN; k0 += 16) {
        const float4 av = *(const float4*)&A[(size_t)(m0 + lr) * IN + k0 + lk];
        const float4 bv = *(const float4*)&B[(size_t)(n0 + lr) * IN + k0 + lk];
        __syncthreads();
        As[lr][lk + 0] = av.x; As[lr][lk + 1] = av.y;
        As[lr][lk + 2] = av.z; As[lr][lk + 3] = av.w;
        Bs[lr][lk + 0] = bv.x; Bs[lr][lk + 1] = bv.y;
        Bs[lr][lk + 2] = bv.z; Bs[lr][lk + 3] = bv.w;
        __syncthreads();
#pragma unroll
        for (int k = 0; k < 16; ++k) {
            float a[4], b[4];
#pragma unroll
            for (int i = 0; i < 4; ++i) a[i] = As[ty * 4 + i][k];
#pragma unroll
            for (int j = 0; j < 4; ++j) b[j] = Bs[tx * 4 + j][k];
#pragma unroll
            for (int i = 0; i < 4; ++i)
#pragma unroll
                for (int j = 0; j < 4; ++j) acc[i][j] += a[i] * b[j];
        }
    }
#pragma unroll
    for (int i = 0; i < 4; ++i) {
        float4 v = make_float4(acc[i][0], acc[i][1], acc[i][2], acc[i][3]);
        *(float4*)&out[(size_t)(m0 + ty * 4 + i + 1) * RS + n0 + tx * 4] = v;
    }
}

// fast tanh: 1 - 2/(exp(2x)+1); exact saturation at +/-inf, ~1e-7 rel err.
__device__ __forceinline__ float fast_tanh(float x) {
    float e = __expf(2.0f * x);
    return 1.0f - 2.0f * __builtin_amdgcn_rcpf(e + 1.0f);
}

typedef unsigned long long u64;
#define AT_LOAD_U64(p)     __hip_atomic_load((p), __ATOMIC_RELAXED, __HIP_MEMORY_SCOPE_AGENT)
#define AT_STORE_U64(p, v) __hip_atomic_store((p), (v), __ATOMIC_RELAXED, __HIP_MEMORY_SCOPE_AGENT)

// encode a float pair with parity tag in bit0 of each word.
__device__ __forceinline__ u64 enc2(float a, float b, unsigned tag) {
    return (u64)((__float_as_uint(a) & ~1u) | tag) |
           ((u64)((__float_as_uint(b) & ~1u) | tag) << 32);
}

// ---------------------------------------------------------------------------
// Phase 2: persistent scan, FULLY BARRIER-FREE per-wave dataflow.
// 512 waves x 4 rows each (256 blocks x 2 waves). No LDS, no __syncthreads.
// ring: RING rows x RS dwords, memset-0 at call start (tag bit = 0). Epoch e
// lives in row e%8; every dword carries tag bit0 = ((e>>3)&1)^1 (wrap 0 ->
// tag 1, distinct from memset; stale e-8 has opposite parity; skew <= 1 by
// the all-to-all dependency rules out ABA at distance 16).
// Per step t, each wave:
//  - lane<4 preloads pre (overlaps polls);
//  - lane l batch-issues 16 u64 loads covering its 8 W-column fragments
//    (floats 4l+256j .. +3, j=0..7), then consumes fragments IN ORDER,
//    spinning only on not-yet-tagged words and FMA-ing arrived ones --
//    straggler latency hides under compute of earlier fragments;
//  - 7-shfl multi-value butterfly -> lane l holds row (l&3);
//  - lane<4: tanh finish + plain out store; lanes 0,1 publish the wave's 4
//    rows as 2 tagged u64 sc1 stores (16B, fills 1/8 of a ring line; readers
//    tag-check per word so partial-line fill is harmless).
// ---------------------------------------------------------------------------
__global__ __launch_bounds__(BT, 2)
void reservoir_scan_kernel(const float* __restrict__ W_res,
                           const float* __restrict__ init,
                           float* __restrict__ out,
                           unsigned* __restrict__ ring32) {
    u64* ring = (u64*)ring32;
    const int tid  = threadIdx.x;
    const int wave = tid >> 6;
    const int lane = tid & 63;
    const int gw   = blockIdx.x * (BT / 64) + wave;  // 0..511
    const int r0   = gw * 4;                         // first of 4 owned rows

    // --- W rows r0..r0+3 into registers (128 VGPR); pin ---
    float4 w[4][8];
#pragma unroll
    for (int r = 0; r < 4; ++r) {
        const float* wp = W_res + (size_t)(r0 + r) * RS + lane * 4;
#pragma unroll
        for (int j = 0; j < 8; ++j) w[r][j] = *(const float4*)(wp + j * 256);
    }
#pragma unroll
    for (int r = 0; r < 4; ++r)
#pragma unroll
        for (int j = 0; j < 8; ++j)
            asm volatile("" : "+v"(w[r][j].x), "+v"(w[r][j].y),
                              "+v"(w[r][j].z), "+v"(w[r][j].w));

    // --- epoch 0 (wrap 0, tag 1): out row 0 = init; publish own 4 rows ---
    if (lane == 0) {
        float4 v = *(const float4*)(init + r0);
        *(float4*)(out + r0) = v;
        AT_STORE_U64(ring + (r0 >> 1),     enc2(v.x, v.y, 1u));
        AT_STORE_U64(ring + (r0 >> 1) + 1, enc2(v.z, v.w, 1u));
    }

    for (int t = 0; t < SEQ; ++t) {
        const u64* rp = ring + (size_t)(t & (RING - 1)) * (RS / 2);
        u64*       pp = ring + (size_t)((t + 1) & (RING - 1)) * (RS / 2);
        const unsigned tag_c = ((unsigned)(t >> 3) & 1u) ^ 1u;
        const unsigned tag_p = ((unsigned)((t + 1) >> 3) & 1u) ^ 1u;

        // --- lane<4: preload pre early (overlaps the polls) ---
        float pre = 0.f;
        if (lane < 4) pre = out[(size_t)(t + 1) * RS + r0 + lane];

        // --- batch-issue 16 u64 loads: fragment j = floats 4*lane+256j..+3 ---
        u64 q0[8], q1[8];
#pragma unroll
        for (int j = 0; j < 8; ++j) {
            const u64* a = rp + 2 * lane + 128 * j;
            q0[j] = AT_LOAD_U64(a);
            q1[j] = AT_LOAD_U64(a + 1);
        }

        // --- consume fragments in order; FMA overlaps straggler waits ---
        float a0 = 0.f, a1 = 0.f, a2 = 0.f, a3 = 0.f;
#define RDY(x) (((((unsigned)(x) ^ tag_c) | ((unsigned)((x) >> 32) ^ tag_c)) & 1u) == 0u)
#pragma unroll
        for (int j = 0; j < 8; ++j) {
            const u64* a = rp + 2 * lane + 128 * j;
            u64 v0 = q0[j], v1 = q1[j];
            while (!(RDY(v0) && RDY(v1))) {
                v0 = AT_LOAD_U64(a);
                v1 = AT_LOAD_U64(a + 1);
            }
            float4 sv;
            sv.x = __uint_as_float((unsigned)v0);
            sv.y = __uint_as_float((unsigned)(v0 >> 32));
            sv.z = __uint_as_float((unsigned)v1);
            sv.w = __uint_as_float((unsigned)(v1 >> 32));
            a0 += w[0][j].x * sv.x + w[0][j].y * sv.y + w[0][j].z * sv.z + w[0][j].w * sv.w;
            a1 += w[1][j].x * sv.x + w[1][j].y * sv.y + w[1][j].z * sv.z + w[1][j].w * sv.w;
            a2 += w[2][j].x * sv.x + w[2][j].y * sv.y + w[2][j].z * sv.z + w[2][j].w * sv.w;
            a3 += w[3][j].x * sv.x + w[3][j].y * sv.y + w[3][j].z * sv.z + w[3][j].w * sv.w;
        }
#undef RDY

        // --- multi-value butterfly: 7 shfls; lane l ends with row (l&3) ---
        const bool p1 = (lane & 1) != 0;
        float k01 = p1 ? a1 : a0, s01 = p1 ? a0 : a1;
        k01 += __shfl_xor(s01, 1);
        float k23 = p1 ? a3 : a2, s23 = p1 ? a2 : a3;
        k23 += __shfl_xor(s23, 1);
        const bool p2 = (lane & 2) != 0;
        float kk = p2 ? k23 : k01, ss = p2 ? k01 : k23;
        kk += __shfl_xor(ss, 2);
        kk += __shfl_xor(kk, 4);
        kk += __shfl_xor(kk, 8);
        kk += __shfl_xor(kk, 16);
        kk += __shfl_xor(kk, 32);

        // --- lane<4: finish row r0+lane; plain out store ---
        float s = 0.f;
        if (lane < 4) {
            s = fast_tanh(pre + kk) * INV_SQRT;
            out[(size_t)(t + 1) * RS + r0 + lane] = s;
        }

        // --- per-wave publish: lanes 0,1 store 2 tagged u64 (16B total) ---
        float pa = __shfl(s, (lane & 1) * 2);
        float pb = __shfl(s, (lane & 1) * 2 + 1);
        if (lane < 2)
            AT_STORE_U64(pp + (r0 >> 1) + lane, enc2(pa, pb, tag_p));
    }
}

extern "C" void kernel_launch(void* const* d_in, const int* in_sizes, int n_in,
                              void* d_out, int out_size, void* d_ws, size_t ws_size,
                              hipStream_t stream) {
    const float* x     = (const float*)d_in[0];  // (4096, 512)
    const float* init  = (const float*)d_in[1];  // (2048,)
    const float* W_in  = (const float*)d_in[2];  // (2048, 512)
    const float* W_res = (const float*)d_in[3];  // (2048, 2048)
    float* out = (float*)d_out;                  // (4097, 2048)
    unsigned* ring = (unsigned*)d_ws;

    hipMemsetAsync(d_ws, 0, (size_t)RING * RS * sizeof(float), stream);
    gemm_pre_kernel<<<dim3(SEQ / 64, RS / 64), 256, 0, stream>>>(x, W_in, out);

    void* args[] = { (void*)&W_res, (void*)&init, (void*)&out, (void*)&ring };
    hipLaunchCooperativeKernel((void*)reservoir_scan_kernel,
                               dim3(GB), dim3(BT), args, 0, stream);
}

// Round 10
// 7560.436 us; speedup vs baseline: 2.7283x; 2.7283x over previous
//
#include <hip/hip_runtime.h>

constexpr int SEQ  = 4096;   // timesteps
constexpr int IN   = 512;    // input size
constexpr int RS   = 2048;   // reservoir size
constexpr int GB   = 64;     // blocks in scan kernel
constexpr int BT   = 512;    // threads per block (8 waves x 4 rows)
constexpr int RING = 8;      // ring depth (epochs); skew bound <= 1
constexpr float INV_SQRT = 0.022097086912079612f; // 1/sqrt(2048)

// fast tanh: 1 - 2/(exp(2x)+1); exact saturation at +/-inf, ~1e-7 rel err.
__device__ __forceinline__ float fast_tanh(float x) {
    float e = __expf(2.0f * x);
    return 1.0f - 2.0f * __builtin_amdgcn_rcpf(e + 1.0f);
}

typedef unsigned long long u64;
#define AT_LOAD_U64(p)     __hip_atomic_load((p), __ATOMIC_RELAXED, __HIP_MEMORY_SCOPE_AGENT)
#define AT_STORE_U32(p, v) __hip_atomic_store((p), (v), __ATOMIC_RELAXED, __HIP_MEMORY_SCOPE_AGENT)

// ---------------------------------------------------------------------------
// Persistent scan, barrier-free dataflow with EPOCH-PARITY tags (R7 protocol)
// + on-the-fly input projection (no separate GEMM pass) + out-store moved
// off the publish critical path.
//   state_t = tanh(W_in x_t + W_res s_{t-1}) / sqrt(RS)
// ring: RING rows x RS dwords in d_ws, memset-0 at call start (tag bit 0).
// Epoch e lives in row e%8 with tag bit0 = ((e>>3)&1)^1; stale epoch e-8
// carries the opposite tag; skew <= 1 rules out ABA at distance 16.
// No zeroing, no vmcnt drain: publish = bare coalesced 128B sc1 store.
// Block b owns rows [b*32, b*32+32); wave w rows b*32 + 4w + {0..3}.
// Per step: [prefetch x-frag] || [poll 2 u64/thread -> LDS] -> sync1 ->
// acc = W_in-frag . x-frag (pre partial) + W-frags . LDS-state -> 7-shfl
// multi-value butterfly (reduces dot AND pre together) -> lane<4 tanh ->
// s_pub -> sync2 -> wave0 publishes 128B tagged line -> out store (drains
// under next step's poll spin).
// ---------------------------------------------------------------------------
__global__ __launch_bounds__(BT, 2)
void reservoir_scan_kernel(const float* __restrict__ x,
                           const float* __restrict__ init,
                           const float* __restrict__ W_in,
                           const float* __restrict__ W_res,
                           float* __restrict__ out,
                           unsigned* __restrict__ ring32) {
    __shared__ float s_state[RS];
    __shared__ float s_pub[32];
    u64* ring = (u64*)ring32;
    const int bid  = blockIdx.x;
    const int tid  = threadIdx.x;
    const int wave = tid >> 6;
    const int lane = tid & 63;
    const int r0   = bid * 32 + wave * 4;     // first of this wave's 4 rows

    // --- W_res rows r0..r0+3 into registers (128 VGPR); pin ---
    float4 w[4][8];
#pragma unroll
    for (int r = 0; r < 4; ++r) {
        const float* wp = W_res + (size_t)(r0 + r) * RS + lane * 4;
#pragma unroll
        for (int j = 0; j < 8; ++j) w[r][j] = *(const float4*)(wp + j * 256);
    }
#pragma unroll
    for (int r = 0; r < 4; ++r)
#pragma unroll
        for (int j = 0; j < 8; ++j)
            asm volatile("" : "+v"(w[r][j].x), "+v"(w[r][j].y),
                              "+v"(w[r][j].z), "+v"(w[r][j].w));

    // --- W_in rows r0..r0+3, lane covers x-elems [8*lane, 8*lane+8) ---
    float4 wi[4][2];
#pragma unroll
    for (int r = 0; r < 4; ++r) {
        const float* wp = W_in + (size_t)(r0 + r) * IN + lane * 8;
        wi[r][0] = *(const float4*)wp;
        wi[r][1] = *(const float4*)(wp + 4);
    }
#pragma unroll
    for (int r = 0; r < 4; ++r)
#pragma unroll
        for (int j = 0; j < 2; ++j)
            asm volatile("" : "+v"(wi[r][j].x), "+v"(wi[r][j].y),
                              "+v"(wi[r][j].z), "+v"(wi[r][j].w));

    // --- epoch 0 (wrap 0, tag 1): out row 0 = init; publish; seed s_pub ---
    if (wave == 0 && lane < 32) {
        float v = init[bid * 32 + lane];
        out[bid * 32 + lane] = v;
        s_pub[lane] = v;
        AT_STORE_U32(ring32 + bid * 32 + lane, __float_as_uint(v) | 1u);
    }
    __syncthreads();

    for (int t = 0; t < SEQ; ++t) {
        const size_t crow = (size_t)(t & (RING - 1)) * (RS / 2);        // u64
        const size_t prow = (size_t)((t + 1) & (RING - 1)) * RS;        // u32
        const unsigned tag_c = ((unsigned)(t >> 3) & 1u) ^ 1u;          // consume
        const unsigned tag_p = ((unsigned)((t + 1) >> 3) & 1u) ^ 1u;    // publish

        // --- prefetch x fragment for on-the-fly pre (overlaps the poll) ---
        const float* xp = x + (size_t)t * IN + lane * 8;
        float4 xv0 = *(const float4*)xp;
        float4 xv1 = *(const float4*)(xp + 4);

        // --- stage state row t into LDS: thread tid -> floats [4tid,4tid+4) ---
        if ((tid >> 3) == bid) {
            const int k = tid & 7;
            *(float4*)&s_state[4 * tid] = *(const float4*)&s_pub[4 * k];
        } else {
            const u64* pp = ring + crow + 2 * tid;
            u64 v0 = AT_LOAD_U64(pp);
            u64 v1 = AT_LOAD_U64(pp + 1);
#define RDY(v) (((((unsigned)(v) ^ tag_c) | ((unsigned)((v) >> 32) ^ tag_c)) & 1u) == 0u)
            while (!(RDY(v0) && RDY(v1))) {
                v0 = AT_LOAD_U64(pp);
                v1 = AT_LOAD_U64(pp + 1);
            }
#undef RDY
            float4 sv;
            sv.x = __uint_as_float((unsigned)v0);
            sv.y = __uint_as_float((unsigned)(v0 >> 32));
            sv.z = __uint_as_float((unsigned)v1);
            sv.w = __uint_as_float((unsigned)(v1 >> 32));
            *(float4*)&s_state[4 * tid] = sv;
        }
        __syncthreads();

        // --- acc init = pre partial (W_in-frag . x-frag), then the dot ---
        float a0 = wi[0][0].x*xv0.x + wi[0][0].y*xv0.y + wi[0][0].z*xv0.z + wi[0][0].w*xv0.w
                 + wi[0][1].x*xv1.x + wi[0][1].y*xv1.y + wi[0][1].z*xv1.z + wi[0][1].w*xv1.w;
        float a1 = wi[1][0].x*xv0.x + wi[1][0].y*xv0.y + wi[1][0].z*xv0.z + wi[1][0].w*xv0.w
                 + wi[1][1].x*xv1.x + wi[1][1].y*xv1.y + wi[1][1].z*xv1.z + wi[1][1].w*xv1.w;
        float a2 = wi[2][0].x*xv0.x + wi[2][0].y*xv0.y + wi[2][0].z*xv0.z + wi[2][0].w*xv0.w
                 + wi[2][1].x*xv1.x + wi[2][1].y*xv1.y + wi[2][1].z*xv1.z + wi[2][1].w*xv1.w;
        float a3 = wi[3][0].x*xv0.x + wi[3][0].y*xv0.y + wi[3][0].z*xv0.z + wi[3][0].w*xv0.w
                 + wi[3][1].x*xv1.x + wi[3][1].y*xv1.y + wi[3][1].z*xv1.z + wi[3][1].w*xv1.w;
#pragma unroll
        for (int j = 0; j < 8; ++j) {
            const float4 sv = *(const float4*)&s_state[lane * 4 + j * 256];
            a0 += w[0][j].x * sv.x + w[0][j].y * sv.y + w[0][j].z * sv.z + w[0][j].w * sv.w;
            a1 += w[1][j].x * sv.x + w[1][j].y * sv.y + w[1][j].z * sv.z + w[1][j].w * sv.w;
            a2 += w[2][j].x * sv.x + w[2][j].y * sv.y + w[2][j].z * sv.z + w[2][j].w * sv.w;
            a3 += w[3][j].x * sv.x + w[3][j].y * sv.y + w[3][j].z * sv.z + w[3][j].w * sv.w;
        }

        // --- multi-value butterfly: 7 shfls; lane l ends with row (l&3) ---
        // (sums dot AND pre partials across all 64 lanes in one pass)
        const bool p1 = (lane & 1) != 0;
        float k01 = p1 ? a1 : a0, s01 = p1 ? a0 : a1;
        k01 += __shfl_xor(s01, 1);
        float k23 = p1 ? a3 : a2, s23 = p1 ? a2 : a3;
        k23 += __shfl_xor(s23, 1);
        const bool p2 = (lane & 2) != 0;
        float kk = p2 ? k23 : k01, ss = p2 ? k01 : k23;
        kk += __shfl_xor(ss, 2);
        kk += __shfl_xor(kk, 4);
        kk += __shfl_xor(kk, 8);
        kk += __shfl_xor(kk, 16);
        kk += __shfl_xor(kk, 32);

        // --- lane<4: finish row r0+lane; stage decoded value for publish ---
        float sres = 0.f;
        if (lane < 4) {
            sres = fast_tanh(kk) * INV_SQRT;
            s_pub[wave * 4 + lane] = sres;
        }
        __syncthreads();

        // --- publish FIRST: one coalesced 128B sc1 store with parity tag ---
        if (wave == 0 && lane < 32) {
            unsigned bits = __float_as_uint(s_pub[lane]);
            AT_STORE_U32(ring32 + prow + bid * 32 + lane,
                         (bits & ~1u) | tag_p);
        }

        // --- out store AFTER publish: drains under next step's poll spin ---
        if (lane < 4)
            out[(size_t)(t + 1) * RS + r0 + lane] = sres;
    }
}

extern "C" void kernel_launch(void* const* d_in, const int* in_sizes, int n_in,
                              void* d_out, int out_size, void* d_ws, size_t ws_size,
                              hipStream_t stream) {
    const float* x     = (const float*)d_in[0];  // (4096, 512)
    const float* init  = (const float*)d_in[1];  // (2048,)
    const float* W_in  = (const float*)d_in[2];  // (2048, 512)
    const float* W_res = (const float*)d_in[3];  // (2048, 2048)
    float* out = (float*)d_out;                  // (4097, 2048)
    unsigned* ring = (unsigned*)d_ws;

    hipMemsetAsync(d_ws, 0, (size_t)RING * RS * sizeof(float), stream);

    void* args[] = { (void*)&x, (void*)&init, (void*)&W_in, (void*)&W_res,
                     (void*)&out, (void*)&ring };
    hipLaunchCooperativeKernel((void*)reservoir_scan_kernel,
                               dim3(GB), dim3(BT), args, 0, stream);
}